// Round 3
// baseline (63.081 us; speedup 1.0000x reference)
//
#include <hip/hip_runtime.h>
#include <math.h>

#define NPTS 2048
#define NCLS 8
#define CONF 0.5f
#define DTHR 20.0f
#define TOPK 4
#define NT 1024
#define EPT (NPTS / NT)   // 2 points per thread
#define NWAVES (NT / 64)  // 16

// One block per (batch, class). Greedy NMS == iterative max-selection:
//   kept[k] = argmax over still-unsuppressed valid keys; then suppress all
//   points within DTHR of it. Only TOPK=4 iterations needed, no sort.
// Key = (score_bits << 32) | ~n  -> max key == (higher score, then smaller
// original index), matching JAX's stable descending argsort exactly.
// 1024 threads (16 waves) to hide global-load latency; wmax double-buffered
// so each selection iteration needs only ONE barrier.
__global__ __launch_bounds__(NT) void decode_kernel(
    const float* __restrict__ loc,   // [B, N, 2]
    const float* __restrict__ cls,   // [B, N, C]
    float* __restrict__ out)         // [64 scores | 128 points | 64 valid]
{
    __shared__ float px[NPTS];
    __shared__ float py[NPTS];
    __shared__ unsigned long long wmax[2][NWAVES];  // double-buffered per-wave max

    const int b = blockIdx.x >> 3;
    const int c = blockIdx.x & 7;
    const int tid = threadIdx.x;
    const int lane = tid & 63;
    const int wid = tid >> 6;

    unsigned long long key[EPT];
    float mx[EPT], my[EPT];

    // ---- load + softmax score for class c; keys in registers ----
    #pragma unroll
    for (int e = 0; e < EPT; ++e) {
        const int n = tid + e * NT;
        const float* lg = cls + (size_t)(b * NPTS + n) * NCLS;
        float4 a0 = *(const float4*)(lg);
        float4 a1 = *(const float4*)(lg + 4);
        float v[8] = {a0.x, a0.y, a0.z, a0.w, a1.x, a1.y, a1.z, a1.w};
        float m = v[0];
        #pragma unroll
        for (int i = 1; i < 8; ++i) m = fmaxf(m, v[i]);
        float ssum = 0.f, ec = 0.f;
        #pragma unroll
        for (int i = 0; i < 8; ++i) {
            float e2 = expf(v[i] - m);
            ssum += e2;
            if (i == c) ec = e2;
        }
        float s = ec / ssum;
        float2 p = *(const float2*)(loc + (size_t)(b * NPTS + n) * 2);
        px[n] = p.x;
        py[n] = p.y;
        mx[e] = p.x;
        my[e] = p.y;
        key[e] = (s > CONF)
                     ? (((unsigned long long)__float_as_uint(s) << 32) |
                        (unsigned int)(~n))
                     : 0ull;
    }
    __syncthreads();

    float ks[TOPK] = {0.f, 0.f, 0.f, 0.f};
    float kx[TOPK] = {0.f, 0.f, 0.f, 0.f};
    float ky[TOPK] = {0.f, 0.f, 0.f, 0.f};
    int nk = 0;

    for (int it = 0; it < TOPK; ++it) {
        const int buf = it & 1;
        // ---- block-wide max key ----
        unsigned long long m = key[0];
        #pragma unroll
        for (int e = 1; e < EPT; ++e) m = (key[e] > m) ? key[e] : m;
        #pragma unroll
        for (int o = 32; o > 0; o >>= 1) {
            unsigned long long t = __shfl_xor(m, o, 64);
            m = (t > m) ? t : m;
        }
        if (lane == 0) wmax[buf][wid] = m;
        __syncthreads();   // writes of this buf visible; other buf free for next it
        m = wmax[buf][0];
        #pragma unroll
        for (int w = 1; w < NWAVES; ++w)
            m = (wmax[buf][w] > m) ? wmax[buf][w] : m;

        if (m == 0ull) break;   // uniform across block: no candidate left

        const float s = __uint_as_float((unsigned int)(m >> 32));
        const int n = (int)(~(unsigned int)(m & 0xFFFFFFFFull));
        const float sx = px[n];   // LDS broadcast (same address all lanes)
        const float sy = py[n];

        ks[nk] = s; kx[nk] = sx; ky[nk] = sy;
        ++nk;

        // ---- suppress everything within DTHR of the selected point ----
        #pragma unroll
        for (int e = 0; e < EPT; ++e) {
            float dx = mx[e] - sx;
            float dy = my[e] - sy;
            if (sqrtf(__fmul_rn(dx, dx) + __fmul_rn(dy, dy)) <= DTHR)
                key[e] = 0ull;   // also zeroes the selected point itself (d=0)
        }
    }

    // ---- outputs (zeros for invalid slots; d_out is poisoned each launch) ----
    if (tid == 0) {
        const int base = b * NCLS + c;
        float* o_s = out + base * TOPK;            // [B,C,K] scores
        float* o_p = out + 64 + base * TOPK * 2;   // [B,C,K,2] points
        float* o_k = out + 192 + base * TOPK;      // [B,C,K] valid

        #pragma unroll
        for (int k = 0; k < TOPK; ++k) {
            o_s[k] = ks[k];
            o_p[2 * k] = kx[k];
            o_p[2 * k + 1] = ky[k];
            o_k[k] = (nk > k) ? 1.f : 0.f;
        }
    }
}

extern "C" void kernel_launch(void* const* d_in, const int* in_sizes, int n_in,
                              void* d_out, int out_size, void* d_ws, size_t ws_size,
                              hipStream_t stream) {
    const float* loc = (const float*)d_in[0];  // locations [B,N,2]
    const float* cls = (const float*)d_in[1];  // classifications [B,N,C]
    float* out = (float*)d_out;
    decode_kernel<<<16, NT, 0, stream>>>(loc, cls, out);
}